// Round 1
// baseline (11045.686 us; speedup 1.0000x reference)
//
#include <hip/hip_runtime.h>
#include <cstdint>
#include <cstddef>

#define L_SEQ 2048
#define H_DIM 1024
#define NBLK  64      // scan blocks per sequence
#define SCAN_T 512    // threads per scan block

__device__ __forceinline__ float sigmoid_f(float x) {
  return 1.0f / (1.0f + __expf(-x));
}
__device__ __forceinline__ float tanh_f(float x) {
  // 1 - 2/(e^{2x}+1); saturates correctly for large |x|
  return 1.0f - 2.0f / (__expf(2.0f * x) + 1.0f);
}

// ---------------------------------------------------------------------------
// init: zero sync flags, copy h0 into h double-buffer slot 0
// ---------------------------------------------------------------------------
__global__ void init_kernel(const float* __restrict__ h01, const float* __restrict__ h02,
                            float* __restrict__ hbuf1, float* __restrict__ hbuf2,
                            int* __restrict__ flags1, int* __restrict__ flags2) {
  const int tid = threadIdx.x;  // 256 threads
  if (tid < NBLK) { flags1[tid * 32] = 0; flags2[tid * 32] = 0; }
  for (int i = tid; i < H_DIM; i += 256) {
    hbuf1[i] = h01[i];
    hbuf2[i] = h02[i];
  }
}

// ---------------------------------------------------------------------------
// gx = emb[tok] @ W_ih^T + (b_ih + b_hh)   for both sequences
// fused-gather fp32 GEMM: 128x128 tile, BK=16, 256 threads, 8x8 microtile
// ---------------------------------------------------------------------------
__global__ __launch_bounds__(256) void gemm_gx_kernel(
    const int* __restrict__ s1, const int* __restrict__ s2,
    const float* __restrict__ emb, const float* __restrict__ W_ih,
    const float* __restrict__ b_ih, const float* __restrict__ b_hh,
    float* __restrict__ gx1, float* __restrict__ gx2) {
  const int seq = blockIdx.z;
  const int* __restrict__ tok = seq ? s2 : s1;
  float* __restrict__ gx = seq ? gx2 : gx1;
  const int m0 = blockIdx.y * 128;  // token rows
  const int n0 = blockIdx.x * 128;  // gate rows
  const int tid = threadIdx.x;
  const int ti = tid >> 4;   // 0..15
  const int tj = tid & 15;   // 0..15

  __shared__ float As[16][128];
  __shared__ float Bs[16][128];

  const int lr  = tid >> 1;         // 0..127: tile row this thread loads
  const int lk0 = (tid & 1) * 8;    // k-half
  const int arow = tok[m0 + lr];
  const float* aptr = emb + (size_t)arow * H_DIM + lk0;
  const float* bptr = W_ih + (size_t)(n0 + lr) * H_DIM + lk0;

  float acc[8][8];
#pragma unroll
  for (int i = 0; i < 8; ++i)
#pragma unroll
    for (int jj = 0; jj < 8; ++jj) acc[i][jj] = 0.f;

  for (int k0 = 0; k0 < H_DIM; k0 += 16) {
    const float4 av0 = *(const float4*)(aptr + k0);
    const float4 av1 = *(const float4*)(aptr + k0 + 4);
    const float4 bv0 = *(const float4*)(bptr + k0);
    const float4 bv1 = *(const float4*)(bptr + k0 + 4);
    __syncthreads();  // protect previous iteration's LDS reads
    As[lk0 + 0][lr] = av0.x; As[lk0 + 1][lr] = av0.y;
    As[lk0 + 2][lr] = av0.z; As[lk0 + 3][lr] = av0.w;
    As[lk0 + 4][lr] = av1.x; As[lk0 + 5][lr] = av1.y;
    As[lk0 + 6][lr] = av1.z; As[lk0 + 7][lr] = av1.w;
    Bs[lk0 + 0][lr] = bv0.x; Bs[lk0 + 1][lr] = bv0.y;
    Bs[lk0 + 2][lr] = bv0.z; Bs[lk0 + 3][lr] = bv0.w;
    Bs[lk0 + 4][lr] = bv1.x; Bs[lk0 + 5][lr] = bv1.y;
    Bs[lk0 + 6][lr] = bv1.z; Bs[lk0 + 7][lr] = bv1.w;
    __syncthreads();
#pragma unroll
    for (int k = 0; k < 16; ++k) {
      float a[8], bb[8];
      *(float4*)&a[0]  = *(const float4*)&As[k][ti * 8];
      *(float4*)&a[4]  = *(const float4*)&As[k][ti * 8 + 4];
      *(float4*)&bb[0] = *(const float4*)&Bs[k][tj * 8];
      *(float4*)&bb[4] = *(const float4*)&Bs[k][tj * 8 + 4];
#pragma unroll
      for (int i = 0; i < 8; ++i)
#pragma unroll
        for (int jj = 0; jj < 8; ++jj)
          acc[i][jj] = fmaf(a[i], bb[jj], acc[i][jj]);
    }
  }

  float bias[8];
#pragma unroll
  for (int jj = 0; jj < 8; ++jj) {
    const int n = n0 + tj * 8 + jj;
    bias[jj] = b_ih[n] + b_hh[n];
  }
#pragma unroll
  for (int i = 0; i < 8; ++i) {
    const int m = m0 + ti * 8 + i;
    float* dst = gx + (size_t)m * (4 * H_DIM) + n0 + tj * 8;
    float4 o0 = make_float4(acc[i][0] + bias[0], acc[i][1] + bias[1],
                            acc[i][2] + bias[2], acc[i][3] + bias[3]);
    float4 o1 = make_float4(acc[i][4] + bias[4], acc[i][5] + bias[5],
                            acc[i][6] + bias[6], acc[i][7] + bias[7]);
    *(float4*)dst = o0;
    *(float4*)(dst + 4) = o1;
  }
}

// ---------------------------------------------------------------------------
// persistent LSTM scan: 64 blocks/sequence, register-resident W_hh slices.
// Block b owns outputs j in [b*16, b*16+16). Thread (g=tid>>5, u=tid&31):
// output j = b*16+g, k-slice [u*32, u*32+32), all 4 gates -> 128 weight VGPRs.
// Per step: poll flags (state t published by all blocks) -> stage h into LDS
// -> 128 FMA -> 32-lane butterfly reduce -> leaders do gate math, update c,
// publish h[j] (relaxed agent) -> block barrier -> release-store flag.
// h double-buffered by step parity; flags monotone (no reset needed in-loop).
// ---------------------------------------------------------------------------
__global__ __launch_bounds__(SCAN_T, 2) void lstm_scan_kernel(
    const float* __restrict__ W_hh,
    const float* __restrict__ gx1, const float* __restrict__ gx2,
    const float* __restrict__ c01, const float* __restrict__ c02,
    float* __restrict__ hbuf1, float* __restrict__ hbuf2,
    int* __restrict__ flags1, int* __restrict__ flags2) {
  const int blk = blockIdx.x;
  const int seq = (blk >= NBLK) ? 1 : 0;
  const int b = blk - seq * NBLK;
  const float* __restrict__ gx = seq ? gx2 : gx1;
  float* hbuf = seq ? hbuf2 : hbuf1;
  int* flags = seq ? flags2 : flags1;
  const float* c0 = seq ? c02 : c01;

  const int tid = threadIdx.x;
  const int g = tid >> 5;       // 0..15
  const int u = tid & 31;       // 0..31
  const int j = b * 16 + g;     // owned output row

  // load register-resident weight slice: gate q, row q*H+j, cols u*32..+31
  float w[4][32];
#pragma unroll
  for (int q = 0; q < 4; ++q) {
    const float* src = W_hh + (size_t)(q * H_DIM + j) * H_DIM + u * 32;
#pragma unroll
    for (int i = 0; i < 8; ++i) {
      const float4 v = *(const float4*)(src + i * 4);
      w[q][i * 4 + 0] = v.x; w[q][i * 4 + 1] = v.y;
      w[q][i * 4 + 2] = v.z; w[q][i * 4 + 3] = v.w;
    }
  }

  float c = 0.0f;
  if (u == 0) c = c0[j];

  __shared__ float sh[32 * 33];  // 32-chunk layout, +1 pad kills bank conflicts

  for (int t = 0; t < L_SEQ; ++t) {
    // prefetch gx[t] contributions (leaders only; independent of flags)
    float gxv0 = 0.f, gxv1 = 0.f, gxv2 = 0.f, gxv3 = 0.f;
    if (u == 0) {
      const float* gp = gx + (size_t)t * (4 * H_DIM) + j;
      gxv0 = gp[0];
      gxv1 = gp[H_DIM];
      gxv2 = gp[2 * H_DIM];
      gxv3 = gp[3 * H_DIM];
    }
    // wait until every block has published state t
    if (tid < NBLK) {
      while (__hip_atomic_load(flags + tid * 32, __ATOMIC_ACQUIRE,
                               __HIP_MEMORY_SCOPE_AGENT) < t) { }
    }
    __syncthreads();
    // stage h(state t) into LDS
    {
      const float* hsrc = hbuf + ((t & 1) << 10);
      const int i0 = tid * 2;
      const int chunk = i0 >> 5;
      const int off = i0 & 31;
      const float v0 = __hip_atomic_load(hsrc + i0 + 0, __ATOMIC_RELAXED,
                                         __HIP_MEMORY_SCOPE_AGENT);
      const float v1 = __hip_atomic_load(hsrc + i0 + 1, __ATOMIC_RELAXED,
                                         __HIP_MEMORY_SCOPE_AGENT);
      sh[chunk * 33 + off + 0] = v0;
      sh[chunk * 33 + off + 1] = v1;
    }
    __syncthreads();
    // partial dot products for all 4 gates
    float a0 = 0.f, a1 = 0.f, a2 = 0.f, a3 = 0.f;
#pragma unroll
    for (int kk = 0; kk < 32; ++kk) {
      const float hv = sh[u * 33 + kk];
      a0 = fmaf(w[0][kk], hv, a0);
      a1 = fmaf(w[1][kk], hv, a1);
      a2 = fmaf(w[2][kk], hv, a2);
      a3 = fmaf(w[3][kk], hv, a3);
    }
    // butterfly reduce over the 32 k-slices
#pragma unroll
    for (int off = 16; off >= 1; off >>= 1) {
      a0 += __shfl_xor(a0, off, 32);
      a1 += __shfl_xor(a1, off, 32);
      a2 += __shfl_xor(a2, off, 32);
      a3 += __shfl_xor(a3, off, 32);
    }
    if (u == 0) {
      const float gi = a0 + gxv0;
      const float gf = a1 + gxv1;
      const float gg = a2 + gxv2;
      const float go = a3 + gxv3;
      c = sigmoid_f(gf) * c + sigmoid_f(gi) * tanh_f(gg);
      const float hn = sigmoid_f(go) * tanh_f(c);
      __hip_atomic_store(hbuf + (((t + 1) & 1) << 10) + j, hn,
                         __ATOMIC_RELAXED, __HIP_MEMORY_SCOPE_AGENT);
    }
    __syncthreads();
    if (tid == 0) {
      __hip_atomic_store(flags + b * 32, t + 1, __ATOMIC_RELEASE,
                         __HIP_MEMORY_SCOPE_AGENT);
    }
  }
}

// ---------------------------------------------------------------------------
// head: feat = [v1, v2, |v1-v2|, v1*v2]; out = fc2_w @ (fc1_w@feat + fc1_b) + fc2_b
// single block, 512 threads (one per fc1 row)
// ---------------------------------------------------------------------------
__global__ __launch_bounds__(512) void head_kernel(
    const float* __restrict__ h1, const float* __restrict__ h2,
    const float* __restrict__ fc1_w, const float* __restrict__ fc1_b,
    const float* __restrict__ fc2_w, const float* __restrict__ fc2_b,
    float* __restrict__ out) {
  __shared__ float feat[4 * H_DIM];
  __shared__ float yv[512];
  const int tid = threadIdx.x;
  for (int i = tid; i < H_DIM; i += 512) {
    const float a = h1[i], bsv = h2[i];
    feat[i] = a;
    feat[H_DIM + i] = bsv;
    feat[2 * H_DIM + i] = fabsf(a - bsv);
    feat[3 * H_DIM + i] = a * bsv;
  }
  __syncthreads();
  float s = fc1_b[tid];
  const float4* wr = (const float4*)(fc1_w + (size_t)tid * (4 * H_DIM));
#pragma unroll 4
  for (int k4 = 0; k4 < H_DIM; ++k4) {
    const float4 wv = wr[k4];
    const float4 fv = *(const float4*)&feat[k4 * 4];
    s = fmaf(wv.x, fv.x, s);
    s = fmaf(wv.y, fv.y, s);
    s = fmaf(wv.z, fv.z, s);
    s = fmaf(wv.w, fv.w, s);
  }
  yv[tid] = s;
  __syncthreads();
  if (tid < 64) {
    float s0 = 0.f, s1 = 0.f;
    for (int i = tid; i < 512; i += 64) {
      s0 = fmaf(fc2_w[i], yv[i], s0);
      s1 = fmaf(fc2_w[512 + i], yv[i], s1);
    }
#pragma unroll
    for (int off = 32; off >= 1; off >>= 1) {
      s0 += __shfl_down(s0, off);
      s1 += __shfl_down(s1, off);
    }
    if (tid == 0) {
      out[0] = s0 + fc2_b[0];
      out[1] = s1 + fc2_b[1];
    }
  }
}

// ---------------------------------------------------------------------------
extern "C" void kernel_launch(void* const* d_in, const int* in_sizes, int n_in,
                              void* d_out, int out_size, void* d_ws, size_t ws_size,
                              hipStream_t stream) {
  const int*   s1    = (const int*)  d_in[0];
  const int*   s2    = (const int*)  d_in[1];
  const float* emb   = (const float*)d_in[2];
  const float* W_ih  = (const float*)d_in[3];
  const float* W_hh  = (const float*)d_in[4];
  const float* b_ih  = (const float*)d_in[5];
  const float* b_hh  = (const float*)d_in[6];
  const float* h01   = (const float*)d_in[7];
  const float* c01   = (const float*)d_in[8];
  const float* h02   = (const float*)d_in[9];
  const float* c02   = (const float*)d_in[10];
  const float* fc1_w = (const float*)d_in[11];
  const float* fc1_b = (const float*)d_in[12];
  const float* fc2_w = (const float*)d_in[13];
  const float* fc2_b = (const float*)d_in[14];
  float* out = (float*)d_out;

  // workspace layout (fp32 elements)
  const size_t GX = (size_t)L_SEQ * 4 * H_DIM;  // 8M floats per sequence
  float* ws = (float*)d_ws;
  float* gx1 = ws;
  float* gx2 = ws + GX;
  float* hbuf1 = ws + 2 * GX;            // [2][1024] double buffer
  float* hbuf2 = hbuf1 + 2 * H_DIM;
  int* flags1 = (int*)(hbuf2 + 2 * H_DIM);  // 64 flags, 128B stride
  int* flags2 = flags1 + NBLK * 32;

  init_kernel<<<1, 256, 0, stream>>>(h01, h02, hbuf1, hbuf2, flags1, flags2);

  gemm_gx_kernel<<<dim3(32, 16, 2), 256, 0, stream>>>(
      s1, s2, emb, W_ih, b_ih, b_hh, gx1, gx2);

  void* args[] = { (void*)&W_hh, (void*)&gx1, (void*)&gx2, (void*)&c01,
                   (void*)&c02, (void*)&hbuf1, (void*)&hbuf2,
                   (void*)&flags1, (void*)&flags2 };
  hipLaunchCooperativeKernel(reinterpret_cast<void*>(lstm_scan_kernel),
                             dim3(2 * NBLK), dim3(SCAN_T), args, 0, stream);

  head_kernel<<<1, 512, 0, stream>>>(hbuf1, hbuf2, fc1_w, fc1_b, fc2_w, fc2_b, out);
}

// Round 2
// 6697.088 us; speedup vs baseline: 1.6493x; 1.6493x over previous
//
#include <hip/hip_runtime.h>
#include <cstdint>
#include <cstddef>

#define L_SEQ 2048
#define H_DIM 1024
#define NBLK  64      // scan blocks per sequence
#define SCAN_T 512    // threads per scan block

typedef unsigned long long u64;

__device__ __forceinline__ float sigmoid_f(float x) {
  return 1.0f / (1.0f + __expf(-x));
}
__device__ __forceinline__ float tanh_f(float x) {
  return 1.0f - 2.0f / (__expf(2.0f * x) + 1.0f);
}

// ---------------------------------------------------------------------------
// init: pack h0 with tag 0 into parity-buffer 0; sentinel tags into buffer 1
// ---------------------------------------------------------------------------
__global__ void init_kernel(const float* __restrict__ h01, const float* __restrict__ h02,
                            u64* __restrict__ hb1, u64* __restrict__ hb2) {
  const int tid = threadIdx.x;  // 256 threads
  for (int i = tid; i < H_DIM; i += 256) {
    hb1[i] = (u64)__float_as_uint(h01[i]);          // tag 0 | h0 bits
    hb2[i] = (u64)__float_as_uint(h02[i]);
    hb1[H_DIM + i] = 0x7FFFFFFFull << 32;           // sentinel tag (never matches)
    hb2[H_DIM + i] = 0x7FFFFFFFull << 32;
  }
}

// ---------------------------------------------------------------------------
// gx = emb[tok] @ W_ih^T + (b_ih + b_hh)   for both sequences
// fused-gather fp32 GEMM: 128x128 tile, BK=16, 256 threads, 8x8 microtile
// ---------------------------------------------------------------------------
__global__ __launch_bounds__(256) void gemm_gx_kernel(
    const int* __restrict__ s1, const int* __restrict__ s2,
    const float* __restrict__ emb, const float* __restrict__ W_ih,
    const float* __restrict__ b_ih, const float* __restrict__ b_hh,
    float* __restrict__ gx1, float* __restrict__ gx2) {
  const int seq = blockIdx.z;
  const int* __restrict__ tok = seq ? s2 : s1;
  float* __restrict__ gx = seq ? gx2 : gx1;
  const int m0 = blockIdx.y * 128;  // token rows
  const int n0 = blockIdx.x * 128;  // gate rows
  const int tid = threadIdx.x;
  const int ti = tid >> 4;   // 0..15
  const int tj = tid & 15;   // 0..15

  __shared__ float As[16][128];
  __shared__ float Bs[16][128];

  const int lr  = tid >> 1;         // 0..127: tile row this thread loads
  const int lk0 = (tid & 1) * 8;    // k-half
  const int arow = tok[m0 + lr];
  const float* aptr = emb + (size_t)arow * H_DIM + lk0;
  const float* bptr = W_ih + (size_t)(n0 + lr) * H_DIM + lk0;

  float acc[8][8];
#pragma unroll
  for (int i = 0; i < 8; ++i)
#pragma unroll
    for (int jj = 0; jj < 8; ++jj) acc[i][jj] = 0.f;

  for (int k0 = 0; k0 < H_DIM; k0 += 16) {
    const float4 av0 = *(const float4*)(aptr + k0);
    const float4 av1 = *(const float4*)(aptr + k0 + 4);
    const float4 bv0 = *(const float4*)(bptr + k0);
    const float4 bv1 = *(const float4*)(bptr + k0 + 4);
    __syncthreads();  // protect previous iteration's LDS reads
    As[lk0 + 0][lr] = av0.x; As[lk0 + 1][lr] = av0.y;
    As[lk0 + 2][lr] = av0.z; As[lk0 + 3][lr] = av0.w;
    As[lk0 + 4][lr] = av1.x; As[lk0 + 5][lr] = av1.y;
    As[lk0 + 6][lr] = av1.z; As[lk0 + 7][lr] = av1.w;
    Bs[lk0 + 0][lr] = bv0.x; Bs[lk0 + 1][lr] = bv0.y;
    Bs[lk0 + 2][lr] = bv0.z; Bs[lk0 + 3][lr] = bv0.w;
    Bs[lk0 + 4][lr] = bv1.x; Bs[lk0 + 5][lr] = bv1.y;
    Bs[lk0 + 6][lr] = bv1.z; Bs[lk0 + 7][lr] = bv1.w;
    __syncthreads();
#pragma unroll
    for (int k = 0; k < 16; ++k) {
      float a[8], bb[8];
      *(float4*)&a[0]  = *(const float4*)&As[k][ti * 8];
      *(float4*)&a[4]  = *(const float4*)&As[k][ti * 8 + 4];
      *(float4*)&bb[0] = *(const float4*)&Bs[k][tj * 8];
      *(float4*)&bb[4] = *(const float4*)&Bs[k][tj * 8 + 4];
#pragma unroll
      for (int i = 0; i < 8; ++i)
#pragma unroll
        for (int jj = 0; jj < 8; ++jj)
          acc[i][jj] = fmaf(a[i], bb[jj], acc[i][jj]);
    }
  }

  float bias[8];
#pragma unroll
  for (int jj = 0; jj < 8; ++jj) {
    const int n = n0 + tj * 8 + jj;
    bias[jj] = b_ih[n] + b_hh[n];
  }
#pragma unroll
  for (int i = 0; i < 8; ++i) {
    const int m = m0 + ti * 8 + i;
    float* dst = gx + (size_t)m * (4 * H_DIM) + n0 + tj * 8;
    float4 o0 = make_float4(acc[i][0] + bias[0], acc[i][1] + bias[1],
                            acc[i][2] + bias[2], acc[i][3] + bias[3]);
    float4 o1 = make_float4(acc[i][4] + bias[4], acc[i][5] + bias[5],
                            acc[i][6] + bias[6], acc[i][7] + bias[7]);
    *(float4*)dst = o0;
    *(float4*)(dst + 4) = o1;
  }
}

// ---------------------------------------------------------------------------
// persistent LSTM scan, tag-embedded h protocol.
// h words are u64: (step_tag << 32) | f32bits(h). Double-buffered by parity.
// Block b owns rows [b*16, b*16+16). Thread (g=tid>>5, u=tid&31): row b*16+g,
// k-slice [u*32,u*32+32), all 4 gates -> 128 weight VGPRs (pinned via asm).
// Per step: leaders prefetch gx[t]; all threads poll their 2 h-words for
// tag==t, unpack into LDS (double-buffered -> ONE barrier/step); 128 FMAs;
// 32-lane butterfly reduce; leaders do gate math and publish (tag t+1 | h).
// Single-word atomicity of tag+data removes all fences and flags.
// ---------------------------------------------------------------------------
__global__ __launch_bounds__(SCAN_T, 2) void lstm_scan_kernel(
    const float* __restrict__ W_hh,
    const float* __restrict__ gx1, const float* __restrict__ gx2,
    const float* __restrict__ c01, const float* __restrict__ c02,
    u64* __restrict__ hb1, u64* __restrict__ hb2) {
  const int blk = blockIdx.x;
  const int seq = (blk >= NBLK) ? 1 : 0;
  const int b = blk - seq * NBLK;
  const float* __restrict__ gx = seq ? gx2 : gx1;
  u64* hb = seq ? hb2 : hb1;
  const float* c0 = seq ? c02 : c01;

  const int tid = threadIdx.x;
  const int g = tid >> 5;       // 0..15
  const int u = tid & 31;       // 0..31
  const int j = b * 16 + g;     // owned output row

  // register-resident weight slice: gate q, row q*H+j, cols u*32..+31
  float w[4][32];
#pragma unroll
  for (int q = 0; q < 4; ++q) {
    const float* src = W_hh + (size_t)(q * H_DIM + j) * H_DIM + u * 32;
#pragma unroll
    for (int i = 0; i < 8; ++i) {
      const float4 v = *(const float4*)(src + i * 4);
      w[q][i * 4 + 0] = v.x; w[q][i * 4 + 1] = v.y;
      w[q][i * 4 + 2] = v.z; w[q][i * 4 + 3] = v.w;
    }
  }
  // pin: forbid rematerialization of the loads inside the t-loop
#pragma unroll
  for (int q = 0; q < 4; ++q)
#pragma unroll
    for (int i = 0; i < 8; ++i)
      asm volatile("" : "+v"(w[q][i * 4 + 0]), "+v"(w[q][i * 4 + 1]),
                        "+v"(w[q][i * 4 + 2]), "+v"(w[q][i * 4 + 3]));

  float c = (u == 0) ? c0[j] : 0.0f;

  __shared__ float sh[2][32 * 33];  // double-buffered, +1 pad per 32-chunk

  const int i0 = tid * 2;           // this thread's 2 h-word slots
  const int ch = i0 >> 5;
  const int off = i0 & 31;

  for (int t = 0; t < L_SEQ; ++t) {
    // prefetch gx[t] contributions (leaders only; independent of h)
    float gxv0 = 0.f, gxv1 = 0.f, gxv2 = 0.f, gxv3 = 0.f;
    if (u == 0) {
      const float* gp = gx + (size_t)t * (4 * H_DIM) + j;
      gxv0 = gp[0];
      gxv1 = gp[H_DIM];
      gxv2 = gp[2 * H_DIM];
      gxv3 = gp[3 * H_DIM];
    }
    // poll h-words of state t directly (tag embedded in the same 64b atom)
    const u64* src = hb + ((t & 1) << 10);
    const unsigned tg = (unsigned)t;
    u64 w0, w1;
    do {
      w0 = __hip_atomic_load(src + i0, __ATOMIC_RELAXED, __HIP_MEMORY_SCOPE_AGENT);
    } while ((unsigned)(w0 >> 32) != tg);
    do {
      w1 = __hip_atomic_load(src + i0 + 1, __ATOMIC_RELAXED, __HIP_MEMORY_SCOPE_AGENT);
    } while ((unsigned)(w1 >> 32) != tg);
    float* sb = &sh[t & 1][0];
    sb[ch * 33 + off + 0] = __uint_as_float((unsigned)w0);
    sb[ch * 33 + off + 1] = __uint_as_float((unsigned)w1);
    __syncthreads();  // the only barrier per step (LDS dbuf covers WAR)
    // partial dot products for all 4 gates
    float a0 = 0.f, a1 = 0.f, a2 = 0.f, a3 = 0.f;
#pragma unroll
    for (int kk = 0; kk < 32; ++kk) {
      const float hv = sb[u * 33 + kk];
      a0 = fmaf(w[0][kk], hv, a0);
      a1 = fmaf(w[1][kk], hv, a1);
      a2 = fmaf(w[2][kk], hv, a2);
      a3 = fmaf(w[3][kk], hv, a3);
    }
    // butterfly reduce over the 32 k-slices
#pragma unroll
    for (int offx = 16; offx >= 1; offx >>= 1) {
      a0 += __shfl_xor(a0, offx, 32);
      a1 += __shfl_xor(a1, offx, 32);
      a2 += __shfl_xor(a2, offx, 32);
      a3 += __shfl_xor(a3, offx, 32);
    }
    if (u == 0) {
      const float gi = a0 + gxv0;
      const float gf = a1 + gxv1;
      const float gg = a2 + gxv2;
      const float go = a3 + gxv3;
      c = sigmoid_f(gf) * c + sigmoid_f(gi) * tanh_f(gg);
      const float hn = sigmoid_f(go) * tanh_f(c);
      const u64 pk = ((u64)(unsigned)(t + 1) << 32) | (u64)__float_as_uint(hn);
      __hip_atomic_store(hb + (((t + 1) & 1) << 10) + j, pk,
                         __ATOMIC_RELAXED, __HIP_MEMORY_SCOPE_AGENT);
    }
  }
}

// ---------------------------------------------------------------------------
// head: feat = [v1, v2, |v1-v2|, v1*v2]; out = fc2_w @ (fc1_w@feat + fc1_b) + fc2_b
// reads the packed final-h buffers (parity 0 holds tag-2048 values)
// ---------------------------------------------------------------------------
__global__ __launch_bounds__(512) void head_kernel(
    const u64* __restrict__ h1p, const u64* __restrict__ h2p,
    const float* __restrict__ fc1_w, const float* __restrict__ fc1_b,
    const float* __restrict__ fc2_w, const float* __restrict__ fc2_b,
    float* __restrict__ out) {
  __shared__ float feat[4 * H_DIM];
  __shared__ float yv[512];
  const int tid = threadIdx.x;
  for (int i = tid; i < H_DIM; i += 512) {
    const float a = __uint_as_float((unsigned)h1p[i]);
    const float bsv = __uint_as_float((unsigned)h2p[i]);
    feat[i] = a;
    feat[H_DIM + i] = bsv;
    feat[2 * H_DIM + i] = fabsf(a - bsv);
    feat[3 * H_DIM + i] = a * bsv;
  }
  __syncthreads();
  float s = fc1_b[tid];
  const float4* wr = (const float4*)(fc1_w + (size_t)tid * (4 * H_DIM));
#pragma unroll 4
  for (int k4 = 0; k4 < H_DIM; ++k4) {
    const float4 wv = wr[k4];
    const float4 fv = *(const float4*)&feat[k4 * 4];
    s = fmaf(wv.x, fv.x, s);
    s = fmaf(wv.y, fv.y, s);
    s = fmaf(wv.z, fv.z, s);
    s = fmaf(wv.w, fv.w, s);
  }
  yv[tid] = s;
  __syncthreads();
  if (tid < 64) {
    float s0 = 0.f, s1 = 0.f;
    for (int i = tid; i < 512; i += 64) {
      s0 = fmaf(fc2_w[i], yv[i], s0);
      s1 = fmaf(fc2_w[512 + i], yv[i], s1);
    }
#pragma unroll
    for (int off = 32; off >= 1; off >>= 1) {
      s0 += __shfl_down(s0, off);
      s1 += __shfl_down(s1, off);
    }
    if (tid == 0) {
      out[0] = s0 + fc2_b[0];
      out[1] = s1 + fc2_b[1];
    }
  }
}

// ---------------------------------------------------------------------------
extern "C" void kernel_launch(void* const* d_in, const int* in_sizes, int n_in,
                              void* d_out, int out_size, void* d_ws, size_t ws_size,
                              hipStream_t stream) {
  const int*   s1    = (const int*)  d_in[0];
  const int*   s2    = (const int*)  d_in[1];
  const float* emb   = (const float*)d_in[2];
  const float* W_ih  = (const float*)d_in[3];
  const float* W_hh  = (const float*)d_in[4];
  const float* b_ih  = (const float*)d_in[5];
  const float* b_hh  = (const float*)d_in[6];
  const float* h01   = (const float*)d_in[7];
  const float* c01   = (const float*)d_in[8];
  const float* h02   = (const float*)d_in[9];
  const float* c02   = (const float*)d_in[10];
  const float* fc1_w = (const float*)d_in[11];
  const float* fc1_b = (const float*)d_in[12];
  const float* fc2_w = (const float*)d_in[13];
  const float* fc2_b = (const float*)d_in[14];
  float* out = (float*)d_out;

  // workspace layout
  const size_t GX = (size_t)L_SEQ * 4 * H_DIM;  // 8M floats per sequence
  float* ws = (float*)d_ws;
  float* gx1 = ws;
  float* gx2 = ws + GX;
  u64* hb1 = (u64*)(ws + 2 * GX);      // [2][1024] packed (tag|h) double buffer
  u64* hb2 = hb1 + 2 * H_DIM;

  init_kernel<<<1, 256, 0, stream>>>(h01, h02, hb1, hb2);

  gemm_gx_kernel<<<dim3(32, 16, 2), 256, 0, stream>>>(
      s1, s2, emb, W_ih, b_ih, b_hh, gx1, gx2);

  void* args[] = { (void*)&W_hh, (void*)&gx1, (void*)&gx2, (void*)&c01,
                   (void*)&c02, (void*)&hb1, (void*)&hb2 };
  hipLaunchCooperativeKernel(reinterpret_cast<void*>(lstm_scan_kernel),
                             dim3(2 * NBLK), dim3(SCAN_T), args, 0, stream);

  head_kernel<<<1, 512, 0, stream>>>(hb1, hb2, fc1_w, fc1_b, fc2_w, fc2_b, out);
}